// Round 7
// baseline (8379.042 us; speedup 1.0000x reference)
//
#include <hip/hip_runtime.h>
#include <math.h>

namespace {

constexpr int BB = 4;
constexpr int N0 = 16384;
constexpr int S1 = 2048;
constexpr int S2 = 1024;

// ---- exact f32 helpers (no contraction) ----
__device__ __forceinline__ float sq3(float x, float y, float z){
  #pragma clang fp contract(off)
  return x*x + y*y + z*z;
}
__device__ __forceinline__ float sqdist(float ax,float ay,float az,float bx,float by,float bz){
  #pragma clang fp contract(off)
  float dx = ax-bx; float dy = ay-by; float dz = az-bz;
  return dx*dx + dy*dy + dz*dz;
}
__device__ __forceinline__ float dot3(float ax,float ay,float az,float bx,float by,float bz){
  #pragma clang fp contract(off)
  return ax*bx + ay*by + az*bz;
}
__device__ __forceinline__ float knndist(float qs, float dot, float rs){
  #pragma clang fp contract(off)
  return (qs - 2.0f*dot) + rs;
}

// ---------------- setup: raw f32, point-major layout ----------------
__global__ __launch_bounds__(256) void k_setup(const float* __restrict__ pc,
                                               const float* __restrict__ feat,
                                               float* __restrict__ out_pc,
                                               float* __restrict__ xyz,
                                               float* __restrict__ fN,
                                               float* __restrict__ rsq0)
{
  int t = blockIdx.x*256 + threadIdx.x;
  if (t < BB*3*N0) out_pc[t] = pc[t];
  if (t < BB*N0){
    int b = t >> 14, n = t & (N0-1);
    const float* p = pc + (size_t)b*3*N0;
    float x = p[n], y = p[N0+n], z = p[2*N0+n];
    float* q = xyz + (size_t)t*3;
    q[0]=x; q[1]=y; q[2]=z;
    rsq0[t] = sq3(x,y,z);
    const float* f = feat + (size_t)b*3*N0;
    float* g = fN + (size_t)t*3;
    g[0]=f[n]; g[1]=f[N0+n]; g[2]=f[2*N0+n];
  }
}

// ---------------- FPS ----------------
// Reference semantics (verified, rounds 0-6 all passed): dist in SQUARED domain;
// per wave: msq_w = wave-max dist; s_w = sqrtf(msq_w); lo_w = smallest f32 with
// sqrt_rn(lo_w)==s_w (preimage walk); dist >= lo_w <=> sqrt_rn(dist)==s_w;
// li_w = min ORIGINAL index in wave with dist >= lo_w. Cross-wave 64-bit key
// (s_bits<<32)|~li: max-key == (max s, min idx) == reference argmax, first-idx ties.
//
// ALGORITHM CHANGE (rounds 1-6 lesson): the compiler spills any >~30 values
// kept across this loop (6 mechanisms tried, all failed at 52-96 VGPRs), so a
// full-N rescan pays ~200KB/iter through one CU = ~2us/iter floor, data
// location irrelevant. Bucket-skip FPS (QuickFPS) removes the rescan:
// Morton-sorted points -> 1024 buckets of 16 per batch; thread=bucket keeps
// dist[16]+bbox(6)+bmax(1) (~25 regs, inside the proven-safe zone; NO pins —
// coord loads are INTENDED in-loop, predicated). Per pick, skip bucket iff
// lb = d^2(centroid, bbox) >= bmax (lb scaled by 0.99999f => skip provably
// safe; margin errs toward streaming; streamed update path is bit-identical
// to the verified one). Dists only decrease; skipped buckets keep exact bmax,
// so selection semantics are unchanged. Ties use ORIGINAL indices via perm
// (LDS-resident). Sort quality affects only speed, never correctness.
__device__ __forceinline__ void fps_writeout(int b, int i, float cx, float cy, float cz, int far,
                                             float* sxyz, float* srsq, float* pcl, float* fidxf, int NP)
{
  fidxf[(size_t)b*NP + i] = (float)far;
  float* o = sxyz + ((size_t)b*NP + i)*3;
  o[0]=cx; o[1]=cy; o[2]=cz;
  float* pb = pcl + (size_t)b*3*NP;
  pb[i] = cx; pb[NP+i] = cy; pb[2*NP+i] = cz;
  srsq[(size_t)b*NP + i] = sq3(cx,cy,cz);
}

// ---- Morton cell machinery (quality-only; correctness independent) ----
__device__ __forceinline__ int fps_quant(float v){
  int q = (int)((v + 5.0f) * 1.6f);          // [-5,5) -> [0,16)
  return q < 0 ? 0 : (q > 15 ? 15 : q);
}
__device__ __forceinline__ int fps_mort(int qx,int qy,int qz){
  int c = 0;
  #pragma unroll
  for (int i=0;i<4;i++){
    c |= (((qx>>i)&1)<<(3*i)) | (((qy>>i)&1)<<(3*i+1)) | (((qz>>i)&1)<<(3*i+2));
  }
  return c;
}

__global__ __launch_bounds__(256) void k_cell(const float* __restrict__ xyz,
                                              int* __restrict__ cellid,
                                              unsigned* __restrict__ hist)
{
  int t = blockIdx.x*256 + threadIdx.x;      // [0, BB*N0)
  int b = t >> 14;
  const float* p = xyz + (size_t)t*3;
  int code = fps_mort(fps_quant(p[0]), fps_quant(p[1]), fps_quant(p[2]));
  cellid[t] = code;
  atomicAdd(&hist[b*4096 + code], 1u);
}

__global__ __launch_bounds__(1024) void k_scan(const unsigned* __restrict__ hist,
                                               unsigned* __restrict__ cstart)
{
  int b = blockIdx.x, t = threadIdx.x, lane = t & 63, wid = t >> 6;
  unsigned v0 = hist[b*4096 + 4*t+0];
  unsigned v1 = hist[b*4096 + 4*t+1];
  unsigned v2 = hist[b*4096 + 4*t+2];
  unsigned v3 = hist[b*4096 + 4*t+3];
  unsigned s = v0+v1+v2+v3;
  unsigned inc = s;
  #pragma unroll
  for (int off=1; off<64; off<<=1){
    unsigned o = __shfl_up(inc, off);
    if (lane >= off) inc += o;
  }
  __shared__ unsigned wsum[16];
  if (lane == 63) wsum[wid] = inc;
  __syncthreads();
  unsigned woff = 0;
  #pragma unroll
  for (int w=0; w<16; w++) if (w < wid) woff += wsum[w];
  unsigned exc = woff + (inc - s);
  cstart[b*4096 + 4*t+0] = exc;
  cstart[b*4096 + 4*t+1] = exc + v0;
  cstart[b*4096 + 4*t+2] = exc + v0 + v1;
  cstart[b*4096 + 4*t+3] = exc + v0 + v1 + v2;
}

__global__ __launch_bounds__(256) void k_scatter(const float* __restrict__ xyz,
                                                 const int* __restrict__ cellid,
                                                 const unsigned* __restrict__ cstart,
                                                 unsigned* __restrict__ ccur,
                                                 float* __restrict__ srtxyz,
                                                 int* __restrict__ perm)
{
  int t = blockIdx.x*256 + threadIdx.x;      // [0, BB*N0)
  int b = t >> 14, n = t & (N0-1);
  int code = cellid[t];
  unsigned pos = cstart[b*4096 + code] + atomicAdd(&ccur[b*4096 + code], 1u);
  size_t d = (size_t)b*N0 + pos;
  const float* p = xyz + (size_t)t*3;
  float* o = srtxyz + d*3;
  o[0]=p[0]; o[1]=p[1]; o[2]=p[2];
  perm[d] = n;
}

// bucket-skip FPS for SA1: 1024 threads = 1024 buckets x 16 sorted points.
__global__ __launch_bounds__(1024) void k_fps1(const float* __restrict__ srtxyz,
                                               const int* __restrict__ permg,
                                               const float* __restrict__ xyz,   // original order
                                               float* __restrict__ sxyz,
                                               float* __restrict__ srsq,
                                               float* __restrict__ pcl,
                                               float* __restrict__ fidxf)
{
  constexpr int NP = S1;
  constexpr int NW = 16;
  int b = blockIdx.x, t = threadIdx.x;
  int lane = t & 63, wid = t >> 6;
  const float* S  = srtxyz + (size_t)b*N0*3;
  const int*   PM = permg  + (size_t)b*N0;
  const float* PO = xyz    + (size_t)b*N0*3;

  __shared__ int s_perm[N0];                 // 64 KB: original indices, sorted order
  __shared__ unsigned long long slot[2][NW];
  for (int i=t; i<N0; i+=1024) s_perm[i] = PM[i];

  float dist[16];
  float bxmin=1e30f,bxmax=-1e30f,bymin=1e30f,bymax=-1e30f,bzmin=1e30f,bzmax=-1e30f;
  #pragma unroll
  for (int j=0;j<16;j++){
    const float* pp = S + (size_t)(t*16+j)*3;
    float x=pp[0], y=pp[1], z=pp[2];
    bxmin=fminf(bxmin,x); bxmax=fmaxf(bxmax,x);
    bymin=fminf(bymin,y); bymax=fmaxf(bymax,y);
    bzmin=fminf(bzmin,z); bzmax=fmaxf(bzmax,z);
    dist[j] = 1e10f;
  }
  float bmax = 1e10f;
  __syncthreads();                           // s_perm ready

  float cx = PO[0], cy = PO[1], cz = PO[2];  // pick 0 = original index 0
  if (t == 0) fps_writeout(b, 0, cx, cy, cz, 0, sxyz, srsq, pcl, fidxf, NP);

  for (int i=1;i<NP;i++){
    int par = i & 1;
    // bucket lower bound: distance^2 from centroid to bbox (clamp = closest pt)
    float qx = fminf(fmaxf(cx, bxmin), bxmax);
    float qy = fminf(fmaxf(cy, bymin), bymax);
    float qz = fminf(fmaxf(cz, bzmin), bzmax);
    float lb = sqdist(qx,qy,qz,cx,cy,cz);
    if (lb*0.99999f < bmax){                 // stream + update (exact path)
      float nm = -1.0f;
      #pragma unroll
      for (int j=0;j<16;j++){
        const float* pp = S + (size_t)(t*16+j)*3;
        float d  = sqdist(pp[0],pp[1],pp[2],cx,cy,cz);
        float nd = fminf(dist[j], d);
        dist[j]  = nd;
        nm = fmaxf(nm, nd);
      }
      bmax = nm;
    }
    // wave-max of squared dist
    float msq = bmax;
    #pragma unroll
    for (int off=32; off>0; off>>=1) msq = fmaxf(msq, __shfl_xor(msq, off));
    // wave-uniform sqrt-preimage lower edge
    float s = sqrtf(msq);
    unsigned xb = __float_as_uint(msq);
    while (xb > 0u && sqrtf(__uint_as_float(xb - 1u)) == s) xb--;
    float lo = __uint_as_float(xb);
    // min ORIGINAL index in this wave's tie set
    int li = 0x7FFFFFFF;
    if (bmax >= lo){
      #pragma unroll
      for (int j=0;j<16;j++) if (dist[j] >= lo) li = min(li, s_perm[t*16+j]);
    }
    #pragma unroll
    for (int off=32; off>0; off>>=1) li = min(li, __shfl_xor(li, off));
    if (lane == 0)
      slot[par][wid] = ((unsigned long long)__float_as_uint(s) << 32)
                     | (unsigned long long)(unsigned)(~li);
    __syncthreads();                         // single barrier per pick
    unsigned long long best = slot[par][0];
    #pragma unroll
    for (int w=1; w<NW; w++){
      unsigned long long o = slot[par][w];
      best = (o > best) ? o : best;
    }
    int far = (int)(~(unsigned)best);
    far = __builtin_amdgcn_readfirstlane(far);
    cx = PO[(size_t)far*3]; cy = PO[(size_t)far*3+1]; cz = PO[(size_t)far*3+2];
    if (t == 0) fps_writeout(b, i, cx, cy, cz, far, sxyz, srsq, pcl, fidxf, NP);
  }
}

// full-scan FPS (verified r1 structure: arrays, no pins, single barrier) — SA2 only.
template<int N, int NP, int BS, int PPT>
__global__ __launch_bounds__(BS) void k_fps_scan(const float* __restrict__ pts,
                                                 float* __restrict__ sxyz,
                                                 float* __restrict__ srsq,
                                                 float* __restrict__ pcl,
                                                 float* __restrict__ fidxf)
{
  static_assert(N == BS*PPT, "bad fps shape");
  constexpr int NW = BS/64;
  int b = blockIdx.x, t = threadIdx.x;
  int lane = t & 63, wid = t >> 6;
  const float* P = pts + (size_t)b*N*3;
  __shared__ unsigned long long slot[2][NW];
  float px[PPT], py[PPT], pz[PPT], dist[PPT];
  #pragma unroll
  for (int j=0;j<PPT;j++){
    int g = t + BS*j;
    px[j]=P[g*3]; py[j]=P[g*3+1]; pz[j]=P[g*3+2];
    dist[j]=1e10f;
  }
  float cx = P[0], cy = P[1], cz = P[2];
  if (t == 0) fps_writeout(b, 0, cx, cy, cz, 0, sxyz, srsq, pcl, fidxf, NP);
  for (int i=1;i<NP;i++){
    int par = i & 1;
    float msq = -1.0f;
    #pragma unroll
    for (int j=0;j<PPT;j++){
      float d  = sqdist(px[j],py[j],pz[j],cx,cy,cz);
      float nd = fminf(dist[j], d);
      dist[j]  = nd;
      msq = fmaxf(msq, nd);
    }
    #pragma unroll
    for (int off=32; off>0; off>>=1) msq = fmaxf(msq, __shfl_xor(msq, off));
    float s = sqrtf(msq);
    unsigned xb = __float_as_uint(msq);
    while (xb > 0u && sqrtf(__uint_as_float(xb - 1u)) == s) xb--;
    float lo = __uint_as_float(xb);
    int li = 0x7FFFFFFF;
    #pragma unroll
    for (int j=PPT-1;j>=0;j--) if (dist[j] >= lo) li = t + BS*j;
    #pragma unroll
    for (int off=32; off>0; off>>=1) li = min(li, __shfl_xor(li, off));
    if (lane == 0)
      slot[par][wid] = ((unsigned long long)__float_as_uint(s) << 32)
                     | (unsigned long long)(unsigned)(~li);
    __syncthreads();
    unsigned long long best = slot[par][0];
    #pragma unroll
    for (int w=1; w<NW; w++){
      unsigned long long o = slot[par][w];
      best = (o > best) ? o : best;
    }
    int far = (int)(~(unsigned)best);
    far = __builtin_amdgcn_readfirstlane(far);
    cx = P[(size_t)far*3]; cy = P[(size_t)far*3+1]; cz = P[(size_t)far*3+2];
    if (t == 0) fps_writeout(b, i, cx, cy, cz, far, sxyz, srsq, pcl, fidxf, NP);
  }
}

// ---------------- exact kNN (32 smallest) via radix select ----------------
template<int NREF, int PPT, int NQ>
__global__ __launch_bounds__(512) void k_knn(const float* __restrict__ qxyz,
                                             const float* __restrict__ qrsq,
                                             const float* __restrict__ rxyz,
                                             const float* __restrict__ rrsq,
                                             int* __restrict__ nidx)
{
  static_assert(NREF == 512*PPT, "bad knn shape");
  int q = blockIdx.x;
  int b = q / NQ;
  int t = threadIdx.x;
  const float* R  = rxyz + (size_t)b*NREF*3;
  const float* RS = rrsq + (size_t)b*NREF;
  float qx = qxyz[(size_t)q*3], qy = qxyz[(size_t)q*3+1], qz = qxyz[(size_t)q*3+2];
  float qs = qrsq[q];
  unsigned u[PPT];
  #pragma unroll
  for (int j=0;j<PPT;j++){
    int g = t + 512*j;
    float rx=R[g*3], ry=R[g*3+1], rz=R[g*3+2];
    float d = knndist(qs, dot3(qx,qy,qz,rx,ry,rz), RS[g]);
    unsigned bu = __float_as_uint(d);
    u[j] = ((int)bu < 0) ? ~bu : (bu | 0x80000000u);
  }
  __shared__ unsigned hist[256];
  __shared__ unsigned s_pref, s_pm, s_want, s_cnteq;
  __shared__ int s_n;
  __shared__ int s_eq[1024];
  __shared__ int s_ne;
  if (t == 0){ s_pref=0u; s_pm=0u; s_want=32u; s_n=0; s_ne=0; }

  for (int shift=24; shift>=0; shift-=8){
    if (t < 256) hist[t] = 0u;
    __syncthreads();
    unsigned pref = s_pref, pm = s_pm;
    #pragma unroll
    for (int j=0;j<PPT;j++){
      if ((u[j] & pm) == pref) atomicAdd(&hist[(u[j]>>shift)&255], 1u);
    }
    __syncthreads();
    if (t < 64){
      unsigned h0=hist[4*t], h1=hist[4*t+1], h2=hist[4*t+2], h3=hist[4*t+3];
      unsigned ssum = h0+h1+h2+h3;
      unsigned inc = ssum;
      #pragma unroll
      for (int off=1; off<64; off<<=1){
        unsigned o = __shfl_up(inc, off);
        if (t >= off) inc += o;
      }
      unsigned exc = inc - ssum;
      unsigned want = s_want;
      if (exc < want && want <= inc){
        unsigned rem = want - exc;
        unsigned bin, below;
        if      (rem <= h0)       { bin=4*t+0; below=exc; }
        else if (rem <= h0+h1)    { bin=4*t+1; below=exc+h0; }
        else if (rem <= h0+h1+h2) { bin=4*t+2; below=exc+h0+h1; }
        else                      { bin=4*t+3; below=exc+h0+h1+h2; }
        s_pref = pref | (bin << shift);
        s_pm   = pm   | (0xFFu << shift);
        s_want = want - below;
        if (shift == 0) s_cnteq = hist[bin];
      }
    }
    __syncthreads();
  }
  unsigned T = s_pref;
  unsigned krem = s_want;
  unsigned cnteq = s_cnteq;
  int* outq = nidx + (size_t)q*32;
  #pragma unroll
  for (int j=0;j<PPT;j++){
    if (u[j] < T){ int p = atomicAdd(&s_n, 1); outq[p] = t + 512*j; }
  }
  __syncthreads();
  if (cnteq == krem){
    #pragma unroll
    for (int j=0;j<PPT;j++){
      if (u[j] == T){ int p = atomicAdd(&s_n, 1); outq[p] = t + 512*j; }
    }
  } else {
    #pragma unroll
    for (int j=0;j<PPT;j++){
      if (u[j] == T){ int p = atomicAdd(&s_ne, 1); if (p < 1024) s_eq[p] = t + 512*j; }
    }
    __syncthreads();
    if (t == 0){
      int ne = s_ne; if (ne > 1024) ne = 1024;
      int p = s_n;
      int take = (int)krem; if (take > ne) take = ne;
      for (int r=0; r<take; r++){
        int mn = 0x7FFFFFFF, mi = -1;
        for (int e=0; e<ne; e++){ if (s_eq[e] < mn){ mn = s_eq[e]; mi = e; } }
        if (mi < 0) break;
        outq[p++] = mn;
        s_eq[mi] = 0x7FFFFFFF;
      }
    }
  }
}

// ---------------- per-layer sum/sumsq accumulation ----------------
template<int C>
__device__ __forceinline__ void accum_sums(const float* o, int b, float* sums){
  __shared__ float s_sum[C];
  __shared__ float s_ssq[C];
  int t = threadIdx.x;
  if (t < C){ s_sum[t]=0.f; s_ssq[t]=0.f; }
  __syncthreads();
  int lane = t & 63;
  #pragma unroll
  for (int c=0;c<C;c++){
    float v = o[c], v2 = v*v;
    #pragma unroll
    for (int off=32; off>0; off>>=1){ v += __shfl_down(v, off); v2 += __shfl_down(v2, off); }
    if (lane == 0){ atomicAdd(&s_sum[c], v); atomicAdd(&s_ssq[c], v2); }
  }
  __syncthreads();
  if (t < C){
    atomicAdd(&sums[(b*64+t)*2],   s_sum[t]);
    atomicAdd(&sums[(b*64+t)*2+1], s_ssq[t]);
  }
}

// ---------------- SA1 layer 1 ----------------
__global__ __launch_bounds__(256) void k_sa1_l1(const float* __restrict__ xyz,
                                                const float* __restrict__ fN,
                                                const float* __restrict__ sxyz,
                                                const int* __restrict__ nidx,
                                                const float* __restrict__ W,
                                                float* __restrict__ xout,
                                                float* __restrict__ sums)
{
  __shared__ float sW[192];
  int t = threadIdx.x;
  if (t < 192) sW[t] = W[t];
  int row = blockIdx.x*256 + t;
  int b = row >> 16;
  int sk = row & 65535;
  int s = sk >> 5;
  int nb = nidx[row];
  const float* pr = xyz  + ((size_t)(b*N0 + nb))*3;
  const float* pq = sxyz + ((size_t)(b*S1 + s ))*3;
  const float* pf = fN   + ((size_t)(b*N0 + nb))*3;
  float i0 = pr[0]-pq[0], i1 = pr[1]-pq[1], i2 = pr[2]-pq[2];
  float i3 = pf[0], i4 = pf[1], i5 = pf[2];
  __syncthreads();
  float o[32];
  #pragma unroll
  for (int c=0;c<32;c++){
    float a = i0*sW[c];
    a = fmaf(i1, sW[ 32+c], a);
    a = fmaf(i2, sW[ 64+c], a);
    a = fmaf(i3, sW[ 96+c], a);
    a = fmaf(i4, sW[128+c], a);
    a = fmaf(i5, sW[160+c], a);
    o[c] = a;
    xout[(size_t)c*262144 + row] = a;
  }
  accum_sums<32>(o, b, sums);
}

// ---------------- mid layer ----------------
template<int CIN, int COUT, int LRPB>
__global__ __launch_bounds__(256) void k_sa_mid(const float* __restrict__ xin,
                                                const float* __restrict__ W,
                                                const float* __restrict__ sums_in,
                                                float* __restrict__ xout,
                                                float* __restrict__ sums_out,
                                                int rows_total, float invM)
{
  __shared__ float sW[CIN*COUT];
  __shared__ float s_mu[CIN];
  __shared__ float s_rs[CIN];
  int t = threadIdx.x;
  int row = blockIdx.x*256 + t;
  int bb = (blockIdx.x*256) >> LRPB;
  for (int i=t; i<CIN*COUT; i+=256) sW[i] = W[i];
  if (t < CIN){
    float sm = sums_in[(bb*64+t)*2], sq = sums_in[(bb*64+t)*2+1];
    float mu = sm*invM;
    float var = fmaxf(sq*invM - mu*mu, 0.f);
    s_mu[t] = mu;
    s_rs[t] = 1.0f/sqrtf(var + 1e-5f);
  }
  __syncthreads();
  float o[COUT];
  #pragma unroll
  for (int d=0;d<COUT;d++) o[d] = 0.f;
  #pragma unroll
  for (int c=0;c<CIN;c++){
    float x = xin[(size_t)c*rows_total + row];
    float v = fmaxf((x - s_mu[c])*s_rs[c], 0.f);
    #pragma unroll
    for (int d=0;d<COUT;d++) o[d] = fmaf(v, sW[c*COUT+d], o[d]);
  }
  #pragma unroll
  for (int d=0;d<COUT;d++) xout[(size_t)d*rows_total + row] = o[d];
  accum_sums<COUT>(o, bb, sums_out);
}

// ---------------- SA2 layer 1 ----------------
__global__ __launch_bounds__(256) void k_sa2_l1(const float* __restrict__ xyz1,
                                                const float* __restrict__ feat1,
                                                const float* __restrict__ xyz2,
                                                const int* __restrict__ nidx,
                                                const float* __restrict__ W,
                                                float* __restrict__ xout,
                                                float* __restrict__ sums)
{
  __shared__ float sW[35*64];
  int t = threadIdx.x;
  for (int i=t; i<35*64; i+=256) sW[i] = W[i];
  int row = blockIdx.x*256 + t;
  int b = row >> 15;
  int sk = row & 32767;
  int s = sk >> 5;
  int nb = nidx[row];
  const float* pr = xyz1 + ((size_t)(b*S1 + nb))*3;
  const float* pq = xyz2 + ((size_t)(b*S2 + s ))*3;
  const float* pf = feat1 + ((size_t)(b*S1 + nb))*32;
  float i0 = pr[0]-pq[0], i1 = pr[1]-pq[1], i2 = pr[2]-pq[2];
  float fv[32];
  #pragma unroll
  for (int c=0;c<32;c++) fv[c] = pf[c];
  __syncthreads();
  float o[64];
  #pragma unroll
  for (int d=0;d<64;d++){
    float a = i0*sW[d];
    a = fmaf(i1, sW[ 64+d], a);
    a = fmaf(i2, sW[128+d], a);
    o[d] = a;
  }
  #pragma unroll
  for (int c=0;c<32;c++){
    float v = fv[c];
    #pragma unroll
    for (int d=0;d<64;d++) o[d] = fmaf(v, sW[(3+c)*64+d], o[d]);
  }
  #pragma unroll
  for (int d=0;d<64;d++) xout[(size_t)d*131072 + row] = o[d];
  accum_sums<64>(o, b, sums);
}

// ---------------- final norm+relu+maxpool ----------------
template<int C, int PTSB, int CF>
__global__ __launch_bounds__(256) void k_pool(const float* __restrict__ xin,
                                              const float* __restrict__ sums_in,
                                              float* __restrict__ out,
                                              int rows_total, float invM)
{
  int t = threadIdx.x;
  int c = t & (C-1);
  int pl = t / C;
  int p = blockIdx.x*(256/C) + pl;
  int b = p / PTSB;
  float sm = sums_in[(b*64+c)*2], sq = sums_in[(b*64+c)*2+1];
  float mu = sm*invM;
  float var = fmaxf(sq*invM - mu*mu, 0.f);
  float rs = 1.0f/sqrtf(var + 1e-5f);
  const float* xp = xin + (size_t)c*rows_total + (size_t)p*32;
  float m = -1e30f;
  #pragma unroll
  for (int k=0;k<32;k++) m = fmaxf(m, xp[k]);
  m = fmaxf((m - mu)*rs, 0.0f);
  if (CF) out[((size_t)(b*C + c))*PTSB + (p - b*PTSB)] = m;
  else    out[(size_t)p*C + c] = m;
}

// ---------------- workspace layout (float element offsets) ----------------
constexpr size_t WS_XYZ   = 0;
constexpr size_t WS_FN    = WS_XYZ   + 196608;
constexpr size_t WS_RSQ0  = WS_FN    + 196608;
constexpr size_t WS_XYZ1  = WS_RSQ0  + 65536;
constexpr size_t WS_RSQ1  = WS_XYZ1  + 24576;
constexpr size_t WS_XYZ2  = WS_RSQ1  + 8192;
constexpr size_t WS_RSQ2  = WS_XYZ2  + 12288;
constexpr size_t WS_FEAT1 = WS_RSQ2  + 4096;
constexpr size_t WS_SUMS  = WS_FEAT1 + 262144;
constexpr size_t WS_BUFA  = WS_SUMS  + 3072;
constexpr size_t WS_BUFB  = WS_BUFA  + 8388608;
constexpr size_t WS_NIDX1 = WS_BUFB  + 8388608;
constexpr size_t WS_NIDX2 = WS_NIDX1 + 262144;

// sort temporaries live INSIDE bufA (used only before k_sa1_l1 overwrites it)
constexpr size_t SRT_XYZ    = 0;        // [BB*N0*3] f32
constexpr size_t SRT_PERM   = 196608;   // [BB*N0] i32
constexpr size_t SRT_CELL   = 262144;   // [BB*N0] i32
constexpr size_t SRT_HIST   = 327680;   // [BB*4096] u32
constexpr size_t SRT_CSTART = 344064;   // [BB*4096] u32
constexpr size_t SRT_CCUR   = 360448;   // [BB*4096] u32

// output offsets (float elements)
constexpr size_t OUT1 = 196608;   // pc_l1 [4][3][2048]
constexpr size_t OUT2 = 221184;   // pc_l2 [4][3][1024]
constexpr size_t OUT3 = 233472;   // feat_l2 [4][64][1024]
constexpr size_t OUT4 = 495616;   // fidx1 [4][2048] (float)
constexpr size_t OUT5 = 503808;   // fidx2 [4][1024] (float)

} // namespace

extern "C" void kernel_launch(void* const* d_in, const int* in_sizes, int n_in,
                              void* d_out, int out_size, void* d_ws, size_t ws_size,
                              hipStream_t stream)
{
  (void)in_sizes; (void)n_in; (void)out_size; (void)ws_size;
  const float* pc   = (const float*)d_in[0];
  const float* feat = (const float*)d_in[1];
  const float* W1 = (const float*)d_in[2];
  const float* W2 = (const float*)d_in[3];
  const float* W3 = (const float*)d_in[4];
  const float* W4 = (const float*)d_in[5];
  const float* W5 = (const float*)d_in[6];
  const float* W6 = (const float*)d_in[7];
  float* out = (float*)d_out;
  float* ws  = (float*)d_ws;

  float* xyz   = ws + WS_XYZ;
  float* fN    = ws + WS_FN;
  float* rsq0  = ws + WS_RSQ0;
  float* xyz1  = ws + WS_XYZ1;
  float* rsq1  = ws + WS_RSQ1;
  float* xyz2  = ws + WS_XYZ2;
  float* rsq2  = ws + WS_RSQ2;
  float* feat1 = ws + WS_FEAT1;
  float* sums  = ws + WS_SUMS;
  float* bufA  = ws + WS_BUFA;
  float* bufB  = ws + WS_BUFB;
  int* nidx1   = (int*)(ws + WS_NIDX1);
  int* nidx2   = (int*)(ws + WS_NIDX2);

  float*    srtxyz = bufA + SRT_XYZ;
  int*      perm   = (int*)     (bufA + SRT_PERM);
  int*      cellid = (int*)     (bufA + SRT_CELL);
  unsigned* hist   = (unsigned*)(bufA + SRT_HIST);
  unsigned* cstart = (unsigned*)(bufA + SRT_CSTART);
  unsigned* ccur   = (unsigned*)(bufA + SRT_CCUR);

  (void)hipMemsetAsync(sums, 0, 3072*sizeof(float), stream);
  (void)hipMemsetAsync(bufA + SRT_HIST, 0, 3*16384*sizeof(unsigned), stream);

  k_setup<<<768, 256, 0, stream>>>(pc, feat, out, xyz, fN, rsq0);

  // ---- SA1 ----
  // Morton counting-sort (quality-only) then bucket-skip FPS.
  k_cell   <<<256, 256, 0, stream>>>(xyz, cellid, hist);
  k_scan   <<<BB, 1024, 0, stream>>>(hist, cstart);
  k_scatter<<<256, 256, 0, stream>>>(xyz, cellid, cstart, ccur, srtxyz, perm);
  k_fps1   <<<BB, 1024, 0, stream>>>(srtxyz, perm, xyz, xyz1, rsq1, out+OUT1, out+OUT4);
  k_knn<N0, 32, S1><<<BB*S1, 512, 0, stream>>>(xyz1, rsq1, xyz, rsq0, nidx1);
  k_sa1_l1<<<1024, 256, 0, stream>>>(xyz, fN, xyz1, nidx1, W1, bufA, sums);
  k_sa_mid<32,32,16><<<1024, 256, 0, stream>>>(bufA, W2, sums,       bufB, sums+512,  262144, 1.0f/65536.0f);
  k_sa_mid<32,32,16><<<1024, 256, 0, stream>>>(bufB, W3, sums+512,   bufA, sums+1024, 262144, 1.0f/65536.0f);
  k_pool<32, 2048, 0><<<1024, 256, 0, stream>>>(bufA, sums+1024, feat1, 262144, 1.0f/65536.0f);

  // ---- SA2 ----
  k_fps_scan<S1, S2, 512, 4><<<BB, 512, 0, stream>>>(xyz1, xyz2, rsq2, out+OUT2, out+OUT5);
  k_knn<S1, 4, S2><<<BB*S2, 512, 0, stream>>>(xyz2, rsq2, xyz1, rsq1, nidx2);
  k_sa2_l1<<<512, 256, 0, stream>>>(xyz1, feat1, xyz2, nidx2, W4, bufB, sums+1536);
  k_sa_mid<64,64,15><<<512, 256, 0, stream>>>(bufB, W5, sums+1536, bufA, sums+2048, 131072, 1.0f/32768.0f);
  k_sa_mid<64,64,15><<<512, 256, 0, stream>>>(bufA, W6, sums+2048, bufB, sums+2560, 131072, 1.0f/32768.0f);
  k_pool<64, 1024, 1><<<1024, 256, 0, stream>>>(bufB, sums+2560, out+OUT3, 131072, 1.0f/32768.0f);
}

// Round 8
// 8317.423 us; speedup vs baseline: 1.0074x; 1.0074x over previous
//
#include <hip/hip_runtime.h>
#include <math.h>

namespace {

constexpr int BB = 4;
constexpr int N0 = 16384;
constexpr int S1 = 2048;
constexpr int S2 = 1024;

// ---- exact f32 helpers (no contraction) ----
__device__ __forceinline__ float sq3(float x, float y, float z){
  #pragma clang fp contract(off)
  return x*x + y*y + z*z;
}
__device__ __forceinline__ float sqdist(float ax,float ay,float az,float bx,float by,float bz){
  #pragma clang fp contract(off)
  float dx = ax-bx; float dy = ay-by; float dz = az-bz;
  return dx*dx + dy*dy + dz*dz;
}
__device__ __forceinline__ float dot3(float ax,float ay,float az,float bx,float by,float bz){
  #pragma clang fp contract(off)
  return ax*bx + ay*by + az*bz;
}
__device__ __forceinline__ float knndist(float qs, float dot, float rs){
  #pragma clang fp contract(off)
  return (qs - 2.0f*dot) + rs;
}

// ---------------- setup: raw f32, point-major layout ----------------
__global__ __launch_bounds__(256) void k_setup(const float* __restrict__ pc,
                                               const float* __restrict__ feat,
                                               float* __restrict__ out_pc,
                                               float* __restrict__ xyz,
                                               float* __restrict__ fN,
                                               float* __restrict__ rsq0)
{
  int t = blockIdx.x*256 + threadIdx.x;
  if (t < BB*3*N0) out_pc[t] = pc[t];
  if (t < BB*N0){
    int b = t >> 14, n = t & (N0-1);
    const float* p = pc + (size_t)b*3*N0;
    float x = p[n], y = p[N0+n], z = p[2*N0+n];
    float* q = xyz + (size_t)t*3;
    q[0]=x; q[1]=y; q[2]=z;
    rsq0[t] = sq3(x,y,z);
    const float* f = feat + (size_t)b*3*N0;
    float* g = fN + (size_t)t*3;
    g[0]=f[n]; g[1]=f[N0+n]; g[2]=f[2*N0+n];
  }
}

// ---------------- FPS ----------------
// Reference semantics (verified rounds 0-7): dist in SQUARED domain; per wave:
// msq_w = wave-max dist; s_w = sqrtf(msq_w); lo_w = smallest f32 with
// sqrt_rn(lo_w)==s_w (preimage walk); dist >= lo_w <=> sqrt_rn(dist)==s_w;
// li_w = min ORIGINAL index in wave with dist >= lo_w. Cross-wave 64-bit key
// (s_bits<<32)|~li: max-key == (max s, min idx) == reference argmax, first-idx ties.
//
// r7 lesson: bucket-skip removed the memory cost but the LOCKSTEP TAIL remained
// ~1.3us/iter of pure instruction issue at 16 waves (45% VALU-busy on active CUs
// in skip mode): two 6-step shfl chains, 16-slot 64-bit scan, barrier — all
// scale with wave count. Fix: BS=512 (8 waves) — halves tail issue and slot
// scan; 512 buckets x 32 points; dist[32] residency proven at BS=512 (r1:
// 88 VGPR, dist[32] in regs through this exact loop shape). Skip condition
// lb*0.99999f < bmax errs toward streaming => provably safe; streamed update
// path identical to verified scan. Sort affects only speed, never correctness.
__device__ __forceinline__ void fps_writeout(int b, int i, float cx, float cy, float cz, int far,
                                             float* sxyz, float* srsq, float* pcl, float* fidxf, int NP)
{
  fidxf[(size_t)b*NP + i] = (float)far;
  float* o = sxyz + ((size_t)b*NP + i)*3;
  o[0]=cx; o[1]=cy; o[2]=cz;
  float* pb = pcl + (size_t)b*3*NP;
  pb[i] = cx; pb[NP+i] = cy; pb[2*NP+i] = cz;
  srsq[(size_t)b*NP + i] = sq3(cx,cy,cz);
}

// ---- Morton cell machinery (quality-only; correctness independent) ----
__device__ __forceinline__ int fps_quant(float v){
  int q = (int)((v + 5.0f) * 1.6f);          // [-5,5) -> [0,16)
  return q < 0 ? 0 : (q > 15 ? 15 : q);
}
__device__ __forceinline__ int fps_mort(int qx,int qy,int qz){
  int c = 0;
  #pragma unroll
  for (int i=0;i<4;i++){
    c |= (((qx>>i)&1)<<(3*i)) | (((qy>>i)&1)<<(3*i+1)) | (((qz>>i)&1)<<(3*i+2));
  }
  return c;
}

__global__ __launch_bounds__(256) void k_cell(const float* __restrict__ xyz,
                                              int* __restrict__ cellid,
                                              unsigned* __restrict__ hist)
{
  int t = blockIdx.x*256 + threadIdx.x;      // [0, BB*N0)
  int b = t >> 14;
  const float* p = xyz + (size_t)t*3;
  int code = fps_mort(fps_quant(p[0]), fps_quant(p[1]), fps_quant(p[2]));
  cellid[t] = code;
  atomicAdd(&hist[b*4096 + code], 1u);
}

__global__ __launch_bounds__(1024) void k_scan(const unsigned* __restrict__ hist,
                                               unsigned* __restrict__ cstart)
{
  int b = blockIdx.x, t = threadIdx.x, lane = t & 63, wid = t >> 6;
  unsigned v0 = hist[b*4096 + 4*t+0];
  unsigned v1 = hist[b*4096 + 4*t+1];
  unsigned v2 = hist[b*4096 + 4*t+2];
  unsigned v3 = hist[b*4096 + 4*t+3];
  unsigned s = v0+v1+v2+v3;
  unsigned inc = s;
  #pragma unroll
  for (int off=1; off<64; off<<=1){
    unsigned o = __shfl_up(inc, off);
    if (lane >= off) inc += o;
  }
  __shared__ unsigned wsum[16];
  if (lane == 63) wsum[wid] = inc;
  __syncthreads();
  unsigned woff = 0;
  #pragma unroll
  for (int w=0; w<16; w++) if (w < wid) woff += wsum[w];
  unsigned exc = woff + (inc - s);
  cstart[b*4096 + 4*t+0] = exc;
  cstart[b*4096 + 4*t+1] = exc + v0;
  cstart[b*4096 + 4*t+2] = exc + v0 + v1;
  cstart[b*4096 + 4*t+3] = exc + v0 + v1 + v2;
}

__global__ __launch_bounds__(256) void k_scatter(const float* __restrict__ xyz,
                                                 const int* __restrict__ cellid,
                                                 const unsigned* __restrict__ cstart,
                                                 unsigned* __restrict__ ccur,
                                                 float* __restrict__ srtxyz,
                                                 int* __restrict__ perm)
{
  int t = blockIdx.x*256 + threadIdx.x;      // [0, BB*N0)
  int b = t >> 14, n = t & (N0-1);
  int code = cellid[t];
  unsigned pos = cstart[b*4096 + code] + atomicAdd(&ccur[b*4096 + code], 1u);
  size_t d = (size_t)b*N0 + pos;
  const float* p = xyz + (size_t)t*3;
  float* o = srtxyz + d*3;
  o[0]=p[0]; o[1]=p[1]; o[2]=p[2];
  perm[d] = n;
}

// bucket-skip FPS: BS threads = BS buckets x PPT sorted points.
template<int N, int NP, int BS, int PPT>
__global__ __launch_bounds__(BS) void k_fps_bucket(const float* __restrict__ srtxyz,
                                                   const int* __restrict__ permg,
                                                   const float* __restrict__ xyz,   // original order
                                                   float* __restrict__ sxyz,
                                                   float* __restrict__ srsq,
                                                   float* __restrict__ pcl,
                                                   float* __restrict__ fidxf)
{
  static_assert(N == BS*PPT, "bad fps shape");
  constexpr int NW = BS/64;
  int b = blockIdx.x, t = threadIdx.x;
  int lane = t & 63, wid = t >> 6;
  const float* S  = srtxyz + (size_t)b*N*3;
  const int*   PM = permg  + (size_t)b*N;
  const float* PO = xyz    + (size_t)b*N*3;

  __shared__ int s_perm[N];                  // original indices, sorted order
  __shared__ unsigned long long slot[2][NW];
  for (int i=t; i<N; i+=BS) s_perm[i] = PM[i];

  float dist[PPT];
  float bxmin=1e30f,bxmax=-1e30f,bymin=1e30f,bymax=-1e30f,bzmin=1e30f,bzmax=-1e30f;
  #pragma unroll
  for (int j=0;j<PPT;j++){
    const float* pp = S + (size_t)(t*PPT+j)*3;
    float x=pp[0], y=pp[1], z=pp[2];
    bxmin=fminf(bxmin,x); bxmax=fmaxf(bxmax,x);
    bymin=fminf(bymin,y); bymax=fmaxf(bymax,y);
    bzmin=fminf(bzmin,z); bzmax=fmaxf(bzmax,z);
    dist[j] = 1e10f;
  }
  float bmax = 1e10f;
  __syncthreads();                           // s_perm ready

  float cx = PO[0], cy = PO[1], cz = PO[2];  // pick 0 = original index 0
  if (t == 0) fps_writeout(b, 0, cx, cy, cz, 0, sxyz, srsq, pcl, fidxf, NP);

  for (int i=1;i<NP;i++){
    int par = i & 1;
    // bucket lower bound: distance^2 from centroid to bbox (clamp = closest pt)
    float qx = fminf(fmaxf(cx, bxmin), bxmax);
    float qy = fminf(fmaxf(cy, bymin), bymax);
    float qz = fminf(fmaxf(cz, bzmin), bzmax);
    float lb = sqdist(qx,qy,qz,cx,cy,cz);
    if (lb*0.99999f < bmax){                 // stream + update (exact path)
      float nm = -1.0f;
      #pragma unroll
      for (int j=0;j<PPT;j++){
        const float* pp = S + (size_t)(t*PPT+j)*3;
        float d  = sqdist(pp[0],pp[1],pp[2],cx,cy,cz);
        float nd = fminf(dist[j], d);
        dist[j]  = nd;
        nm = fmaxf(nm, nd);
      }
      bmax = nm;
    }
    // wave-max of squared dist
    float msq = bmax;
    #pragma unroll
    for (int off=32; off>0; off>>=1) msq = fmaxf(msq, __shfl_xor(msq, off));
    // wave-uniform sqrt-preimage lower edge
    float s = sqrtf(msq);
    unsigned xb = __float_as_uint(msq);
    while (xb > 0u && sqrtf(__uint_as_float(xb - 1u)) == s) xb--;
    float lo = __uint_as_float(xb);
    // min ORIGINAL index in this wave's tie set
    int li = 0x7FFFFFFF;
    if (bmax >= lo){
      #pragma unroll
      for (int j=0;j<PPT;j++) if (dist[j] >= lo) li = min(li, s_perm[t*PPT+j]);
    }
    #pragma unroll
    for (int off=32; off>0; off>>=1) li = min(li, __shfl_xor(li, off));
    if (lane == 0)
      slot[par][wid] = ((unsigned long long)__float_as_uint(s) << 32)
                     | (unsigned long long)(unsigned)(~li);
    __syncthreads();                         // single barrier per pick
    unsigned long long best = slot[par][0];
    #pragma unroll
    for (int w=1; w<NW; w++){
      unsigned long long o = slot[par][w];
      best = (o > best) ? o : best;
    }
    int far = (int)(~(unsigned)best);
    far = __builtin_amdgcn_readfirstlane(far);
    cx = PO[(size_t)far*3]; cy = PO[(size_t)far*3+1]; cz = PO[(size_t)far*3+2];
    if (t == 0) fps_writeout(b, i, cx, cy, cz, far, sxyz, srsq, pcl, fidxf, NP);
  }
}

// full-scan FPS (verified r1 structure) — SA2 only.
template<int N, int NP, int BS, int PPT>
__global__ __launch_bounds__(BS) void k_fps_scan(const float* __restrict__ pts,
                                                 float* __restrict__ sxyz,
                                                 float* __restrict__ srsq,
                                                 float* __restrict__ pcl,
                                                 float* __restrict__ fidxf)
{
  static_assert(N == BS*PPT, "bad fps shape");
  constexpr int NW = BS/64;
  int b = blockIdx.x, t = threadIdx.x;
  int lane = t & 63, wid = t >> 6;
  const float* P = pts + (size_t)b*N*3;
  __shared__ unsigned long long slot[2][NW];
  float px[PPT], py[PPT], pz[PPT], dist[PPT];
  #pragma unroll
  for (int j=0;j<PPT;j++){
    int g = t + BS*j;
    px[j]=P[g*3]; py[j]=P[g*3+1]; pz[j]=P[g*3+2];
    dist[j]=1e10f;
  }
  float cx = P[0], cy = P[1], cz = P[2];
  if (t == 0) fps_writeout(b, 0, cx, cy, cz, 0, sxyz, srsq, pcl, fidxf, NP);
  for (int i=1;i<NP;i++){
    int par = i & 1;
    float msq = -1.0f;
    #pragma unroll
    for (int j=0;j<PPT;j++){
      float d  = sqdist(px[j],py[j],pz[j],cx,cy,cz);
      float nd = fminf(dist[j], d);
      dist[j]  = nd;
      msq = fmaxf(msq, nd);
    }
    #pragma unroll
    for (int off=32; off>0; off>>=1) msq = fmaxf(msq, __shfl_xor(msq, off));
    float s = sqrtf(msq);
    unsigned xb = __float_as_uint(msq);
    while (xb > 0u && sqrtf(__uint_as_float(xb - 1u)) == s) xb--;
    float lo = __uint_as_float(xb);
    int li = 0x7FFFFFFF;
    #pragma unroll
    for (int j=PPT-1;j>=0;j--) if (dist[j] >= lo) li = t + BS*j;
    #pragma unroll
    for (int off=32; off>0; off>>=1) li = min(li, __shfl_xor(li, off));
    if (lane == 0)
      slot[par][wid] = ((unsigned long long)__float_as_uint(s) << 32)
                     | (unsigned long long)(unsigned)(~li);
    __syncthreads();
    unsigned long long best = slot[par][0];
    #pragma unroll
    for (int w=1; w<NW; w++){
      unsigned long long o = slot[par][w];
      best = (o > best) ? o : best;
    }
    int far = (int)(~(unsigned)best);
    far = __builtin_amdgcn_readfirstlane(far);
    cx = P[(size_t)far*3]; cy = P[(size_t)far*3+1]; cz = P[(size_t)far*3+2];
    if (t == 0) fps_writeout(b, i, cx, cy, cz, far, sxyz, srsq, pcl, fidxf, NP);
  }
}

// ---------------- exact kNN (32 smallest) via radix select ----------------
template<int NREF, int PPT, int NQ>
__global__ __launch_bounds__(512) void k_knn(const float* __restrict__ qxyz,
                                             const float* __restrict__ qrsq,
                                             const float* __restrict__ rxyz,
                                             const float* __restrict__ rrsq,
                                             int* __restrict__ nidx)
{
  static_assert(NREF == 512*PPT, "bad knn shape");
  int q = blockIdx.x;
  int b = q / NQ;
  int t = threadIdx.x;
  const float* R  = rxyz + (size_t)b*NREF*3;
  const float* RS = rrsq + (size_t)b*NREF;
  float qx = qxyz[(size_t)q*3], qy = qxyz[(size_t)q*3+1], qz = qxyz[(size_t)q*3+2];
  float qs = qrsq[q];
  unsigned u[PPT];
  #pragma unroll
  for (int j=0;j<PPT;j++){
    int g = t + 512*j;
    float rx=R[g*3], ry=R[g*3+1], rz=R[g*3+2];
    float d = knndist(qs, dot3(qx,qy,qz,rx,ry,rz), RS[g]);
    unsigned bu = __float_as_uint(d);
    u[j] = ((int)bu < 0) ? ~bu : (bu | 0x80000000u);
  }
  __shared__ unsigned hist[256];
  __shared__ unsigned s_pref, s_pm, s_want, s_cnteq;
  __shared__ int s_n;
  __shared__ int s_eq[1024];
  __shared__ int s_ne;
  if (t == 0){ s_pref=0u; s_pm=0u; s_want=32u; s_n=0; s_ne=0; }

  for (int shift=24; shift>=0; shift-=8){
    if (t < 256) hist[t] = 0u;
    __syncthreads();
    unsigned pref = s_pref, pm = s_pm;
    #pragma unroll
    for (int j=0;j<PPT;j++){
      if ((u[j] & pm) == pref) atomicAdd(&hist[(u[j]>>shift)&255], 1u);
    }
    __syncthreads();
    if (t < 64){
      unsigned h0=hist[4*t], h1=hist[4*t+1], h2=hist[4*t+2], h3=hist[4*t+3];
      unsigned ssum = h0+h1+h2+h3;
      unsigned inc = ssum;
      #pragma unroll
      for (int off=1; off<64; off<<=1){
        unsigned o = __shfl_up(inc, off);
        if (t >= off) inc += o;
      }
      unsigned exc = inc - ssum;
      unsigned want = s_want;
      if (exc < want && want <= inc){
        unsigned rem = want - exc;
        unsigned bin, below;
        if      (rem <= h0)       { bin=4*t+0; below=exc; }
        else if (rem <= h0+h1)    { bin=4*t+1; below=exc+h0; }
        else if (rem <= h0+h1+h2) { bin=4*t+2; below=exc+h0+h1; }
        else                      { bin=4*t+3; below=exc+h0+h1+h2; }
        s_pref = pref | (bin << shift);
        s_pm   = pm   | (0xFFu << shift);
        s_want = want - below;
        if (shift == 0) s_cnteq = hist[bin];
      }
    }
    __syncthreads();
  }
  unsigned T = s_pref;
  unsigned krem = s_want;
  unsigned cnteq = s_cnteq;
  int* outq = nidx + (size_t)q*32;
  #pragma unroll
  for (int j=0;j<PPT;j++){
    if (u[j] < T){ int p = atomicAdd(&s_n, 1); outq[p] = t + 512*j; }
  }
  __syncthreads();
  if (cnteq == krem){
    #pragma unroll
    for (int j=0;j<PPT;j++){
      if (u[j] == T){ int p = atomicAdd(&s_n, 1); outq[p] = t + 512*j; }
    }
  } else {
    #pragma unroll
    for (int j=0;j<PPT;j++){
      if (u[j] == T){ int p = atomicAdd(&s_ne, 1); if (p < 1024) s_eq[p] = t + 512*j; }
    }
    __syncthreads();
    if (t == 0){
      int ne = s_ne; if (ne > 1024) ne = 1024;
      int p = s_n;
      int take = (int)krem; if (take > ne) take = ne;
      for (int r=0; r<take; r++){
        int mn = 0x7FFFFFFF, mi = -1;
        for (int e=0; e<ne; e++){ if (s_eq[e] < mn){ mn = s_eq[e]; mi = e; } }
        if (mi < 0) break;
        outq[p++] = mn;
        s_eq[mi] = 0x7FFFFFFF;
      }
    }
  }
}

// ---------------- per-layer sum/sumsq accumulation ----------------
template<int C>
__device__ __forceinline__ void accum_sums(const float* o, int b, float* sums){
  __shared__ float s_sum[C];
  __shared__ float s_ssq[C];
  int t = threadIdx.x;
  if (t < C){ s_sum[t]=0.f; s_ssq[t]=0.f; }
  __syncthreads();
  int lane = t & 63;
  #pragma unroll
  for (int c=0;c<C;c++){
    float v = o[c], v2 = v*v;
    #pragma unroll
    for (int off=32; off>0; off>>=1){ v += __shfl_down(v, off); v2 += __shfl_down(v2, off); }
    if (lane == 0){ atomicAdd(&s_sum[c], v); atomicAdd(&s_ssq[c], v2); }
  }
  __syncthreads();
  if (t < C){
    atomicAdd(&sums[(b*64+t)*2],   s_sum[t]);
    atomicAdd(&sums[(b*64+t)*2+1], s_ssq[t]);
  }
}

// ---------------- SA1 layer 1 ----------------
__global__ __launch_bounds__(256) void k_sa1_l1(const float* __restrict__ xyz,
                                                const float* __restrict__ fN,
                                                const float* __restrict__ sxyz,
                                                const int* __restrict__ nidx,
                                                const float* __restrict__ W,
                                                float* __restrict__ xout,
                                                float* __restrict__ sums)
{
  __shared__ float sW[192];
  int t = threadIdx.x;
  if (t < 192) sW[t] = W[t];
  int row = blockIdx.x*256 + t;
  int b = row >> 16;
  int sk = row & 65535;
  int s = sk >> 5;
  int nb = nidx[row];
  const float* pr = xyz  + ((size_t)(b*N0 + nb))*3;
  const float* pq = sxyz + ((size_t)(b*S1 + s ))*3;
  const float* pf = fN   + ((size_t)(b*N0 + nb))*3;
  float i0 = pr[0]-pq[0], i1 = pr[1]-pq[1], i2 = pr[2]-pq[2];
  float i3 = pf[0], i4 = pf[1], i5 = pf[2];
  __syncthreads();
  float o[32];
  #pragma unroll
  for (int c=0;c<32;c++){
    float a = i0*sW[c];
    a = fmaf(i1, sW[ 32+c], a);
    a = fmaf(i2, sW[ 64+c], a);
    a = fmaf(i3, sW[ 96+c], a);
    a = fmaf(i4, sW[128+c], a);
    a = fmaf(i5, sW[160+c], a);
    o[c] = a;
    xout[(size_t)c*262144 + row] = a;
  }
  accum_sums<32>(o, b, sums);
}

// ---------------- mid layer ----------------
template<int CIN, int COUT, int LRPB>
__global__ __launch_bounds__(256) void k_sa_mid(const float* __restrict__ xin,
                                                const float* __restrict__ W,
                                                const float* __restrict__ sums_in,
                                                float* __restrict__ xout,
                                                float* __restrict__ sums_out,
                                                int rows_total, float invM)
{
  __shared__ float sW[CIN*COUT];
  __shared__ float s_mu[CIN];
  __shared__ float s_rs[CIN];
  int t = threadIdx.x;
  int row = blockIdx.x*256 + t;
  int bb = (blockIdx.x*256) >> LRPB;
  for (int i=t; i<CIN*COUT; i+=256) sW[i] = W[i];
  if (t < CIN){
    float sm = sums_in[(bb*64+t)*2], sq = sums_in[(bb*64+t)*2+1];
    float mu = sm*invM;
    float var = fmaxf(sq*invM - mu*mu, 0.f);
    s_mu[t] = mu;
    s_rs[t] = 1.0f/sqrtf(var + 1e-5f);
  }
  __syncthreads();
  float o[COUT];
  #pragma unroll
  for (int d=0;d<COUT;d++) o[d] = 0.f;
  #pragma unroll
  for (int c=0;c<CIN;c++){
    float x = xin[(size_t)c*rows_total + row];
    float v = fmaxf((x - s_mu[c])*s_rs[c], 0.f);
    #pragma unroll
    for (int d=0;d<COUT;d++) o[d] = fmaf(v, sW[c*COUT+d], o[d]);
  }
  #pragma unroll
  for (int d=0;d<COUT;d++) xout[(size_t)d*rows_total + row] = o[d];
  accum_sums<COUT>(o, bb, sums_out);
}

// ---------------- SA2 layer 1 ----------------
__global__ __launch_bounds__(256) void k_sa2_l1(const float* __restrict__ xyz1,
                                                const float* __restrict__ feat1,
                                                const float* __restrict__ xyz2,
                                                const int* __restrict__ nidx,
                                                const float* __restrict__ W,
                                                float* __restrict__ xout,
                                                float* __restrict__ sums)
{
  __shared__ float sW[35*64];
  int t = threadIdx.x;
  for (int i=t; i<35*64; i+=256) sW[i] = W[i];
  int row = blockIdx.x*256 + t;
  int b = row >> 15;
  int sk = row & 32767;
  int s = sk >> 5;
  int nb = nidx[row];
  const float* pr = xyz1 + ((size_t)(b*S1 + nb))*3;
  const float* pq = xyz2 + ((size_t)(b*S2 + s ))*3;
  const float* pf = feat1 + ((size_t)(b*S1 + nb))*32;
  float i0 = pr[0]-pq[0], i1 = pr[1]-pq[1], i2 = pr[2]-pq[2];
  float fv[32];
  #pragma unroll
  for (int c=0;c<32;c++) fv[c] = pf[c];
  __syncthreads();
  float o[64];
  #pragma unroll
  for (int d=0;d<64;d++){
    float a = i0*sW[d];
    a = fmaf(i1, sW[ 64+d], a);
    a = fmaf(i2, sW[128+d], a);
    o[d] = a;
  }
  #pragma unroll
  for (int c=0;c<32;c++){
    float v = fv[c];
    #pragma unroll
    for (int d=0;d<64;d++) o[d] = fmaf(v, sW[(3+c)*64+d], o[d]);
  }
  #pragma unroll
  for (int d=0;d<64;d++) xout[(size_t)d*131072 + row] = o[d];
  accum_sums<64>(o, b, sums);
}

// ---------------- final norm+relu+maxpool ----------------
template<int C, int PTSB, int CF>
__global__ __launch_bounds__(256) void k_pool(const float* __restrict__ xin,
                                              const float* __restrict__ sums_in,
                                              float* __restrict__ out,
                                              int rows_total, float invM)
{
  int t = threadIdx.x;
  int c = t & (C-1);
  int pl = t / C;
  int p = blockIdx.x*(256/C) + pl;
  int b = p / PTSB;
  float sm = sums_in[(b*64+c)*2], sq = sums_in[(b*64+c)*2+1];
  float mu = sm*invM;
  float var = fmaxf(sq*invM - mu*mu, 0.f);
  float rs = 1.0f/sqrtf(var + 1e-5f);
  const float* xp = xin + (size_t)c*rows_total + (size_t)p*32;
  float m = -1e30f;
  #pragma unroll
  for (int k=0;k<32;k++) m = fmaxf(m, xp[k]);
  m = fmaxf((m - mu)*rs, 0.0f);
  if (CF) out[((size_t)(b*C + c))*PTSB + (p - b*PTSB)] = m;
  else    out[(size_t)p*C + c] = m;
}

// ---------------- workspace layout (float element offsets) ----------------
constexpr size_t WS_XYZ   = 0;
constexpr size_t WS_FN    = WS_XYZ   + 196608;
constexpr size_t WS_RSQ0  = WS_FN    + 196608;
constexpr size_t WS_XYZ1  = WS_RSQ0  + 65536;
constexpr size_t WS_RSQ1  = WS_XYZ1  + 24576;
constexpr size_t WS_XYZ2  = WS_RSQ1  + 8192;
constexpr size_t WS_RSQ2  = WS_XYZ2  + 12288;
constexpr size_t WS_FEAT1 = WS_RSQ2  + 4096;
constexpr size_t WS_SUMS  = WS_FEAT1 + 262144;
constexpr size_t WS_BUFA  = WS_SUMS  + 3072;
constexpr size_t WS_BUFB  = WS_BUFA  + 8388608;
constexpr size_t WS_NIDX1 = WS_BUFB  + 8388608;
constexpr size_t WS_NIDX2 = WS_NIDX1 + 262144;

// sort temporaries live INSIDE bufA (used only before k_sa1_l1 overwrites it)
constexpr size_t SRT_XYZ    = 0;        // [BB*N0*3] f32
constexpr size_t SRT_PERM   = 196608;   // [BB*N0] i32
constexpr size_t SRT_CELL   = 262144;   // [BB*N0] i32
constexpr size_t SRT_HIST   = 327680;   // [BB*4096] u32
constexpr size_t SRT_CSTART = 344064;   // [BB*4096] u32
constexpr size_t SRT_CCUR   = 360448;   // [BB*4096] u32

// output offsets (float elements)
constexpr size_t OUT1 = 196608;   // pc_l1 [4][3][2048]
constexpr size_t OUT2 = 221184;   // pc_l2 [4][3][1024]
constexpr size_t OUT3 = 233472;   // feat_l2 [4][64][1024]
constexpr size_t OUT4 = 495616;   // fidx1 [4][2048] (float)
constexpr size_t OUT5 = 503808;   // fidx2 [4][1024] (float)

} // namespace

extern "C" void kernel_launch(void* const* d_in, const int* in_sizes, int n_in,
                              void* d_out, int out_size, void* d_ws, size_t ws_size,
                              hipStream_t stream)
{
  (void)in_sizes; (void)n_in; (void)out_size; (void)ws_size;
  const float* pc   = (const float*)d_in[0];
  const float* feat = (const float*)d_in[1];
  const float* W1 = (const float*)d_in[2];
  const float* W2 = (const float*)d_in[3];
  const float* W3 = (const float*)d_in[4];
  const float* W4 = (const float*)d_in[5];
  const float* W5 = (const float*)d_in[6];
  const float* W6 = (const float*)d_in[7];
  float* out = (float*)d_out;
  float* ws  = (float*)d_ws;

  float* xyz   = ws + WS_XYZ;
  float* fN    = ws + WS_FN;
  float* rsq0  = ws + WS_RSQ0;
  float* xyz1  = ws + WS_XYZ1;
  float* rsq1  = ws + WS_RSQ1;
  float* xyz2  = ws + WS_XYZ2;
  float* rsq2  = ws + WS_RSQ2;
  float* feat1 = ws + WS_FEAT1;
  float* sums  = ws + WS_SUMS;
  float* bufA  = ws + WS_BUFA;
  float* bufB  = ws + WS_BUFB;
  int* nidx1   = (int*)(ws + WS_NIDX1);
  int* nidx2   = (int*)(ws + WS_NIDX2);

  float*    srtxyz = bufA + SRT_XYZ;
  int*      perm   = (int*)     (bufA + SRT_PERM);
  int*      cellid = (int*)     (bufA + SRT_CELL);
  unsigned* hist   = (unsigned*)(bufA + SRT_HIST);
  unsigned* cstart = (unsigned*)(bufA + SRT_CSTART);
  unsigned* ccur   = (unsigned*)(bufA + SRT_CCUR);

  (void)hipMemsetAsync(sums, 0, 3072*sizeof(float), stream);
  (void)hipMemsetAsync(bufA + SRT_HIST, 0, 3*16384*sizeof(unsigned), stream);

  k_setup<<<768, 256, 0, stream>>>(pc, feat, out, xyz, fN, rsq0);

  // ---- SA1 ----
  // Morton counting-sort (quality-only) then bucket-skip FPS at 8 waves.
  k_cell   <<<256, 256, 0, stream>>>(xyz, cellid, hist);
  k_scan   <<<BB, 1024, 0, stream>>>(hist, cstart);
  k_scatter<<<256, 256, 0, stream>>>(xyz, cellid, cstart, ccur, srtxyz, perm);
  k_fps_bucket<N0, S1, 512, 32><<<BB, 512, 0, stream>>>(srtxyz, perm, xyz, xyz1, rsq1, out+OUT1, out+OUT4);
  k_knn<N0, 32, S1><<<BB*S1, 512, 0, stream>>>(xyz1, rsq1, xyz, rsq0, nidx1);
  k_sa1_l1<<<1024, 256, 0, stream>>>(xyz, fN, xyz1, nidx1, W1, bufA, sums);
  k_sa_mid<32,32,16><<<1024, 256, 0, stream>>>(bufA, W2, sums,       bufB, sums+512,  262144, 1.0f/65536.0f);
  k_sa_mid<32,32,16><<<1024, 256, 0, stream>>>(bufB, W3, sums+512,   bufA, sums+1024, 262144, 1.0f/65536.0f);
  k_pool<32, 2048, 0><<<1024, 256, 0, stream>>>(bufA, sums+1024, feat1, 262144, 1.0f/65536.0f);

  // ---- SA2 ----
  k_fps_scan<S1, S2, 512, 4><<<BB, 512, 0, stream>>>(xyz1, xyz2, rsq2, out+OUT2, out+OUT5);
  k_knn<S1, 4, S2><<<BB*S2, 512, 0, stream>>>(xyz2, rsq2, xyz1, rsq1, nidx2);
  k_sa2_l1<<<512, 256, 0, stream>>>(xyz1, feat1, xyz2, nidx2, W4, bufB, sums+1536);
  k_sa_mid<64,64,15><<<512, 256, 0, stream>>>(bufB, W5, sums+1536, bufA, sums+2048, 131072, 1.0f/32768.0f);
  k_sa_mid<64,64,15><<<512, 256, 0, stream>>>(bufA, W6, sums+2048, bufB, sums+2560, 131072, 1.0f/32768.0f);
  k_pool<64, 1024, 1><<<1024, 256, 0, stream>>>(bufB, sums+2560, out+OUT3, 131072, 1.0f/32768.0f);
}